// Round 4
// baseline (35040.454 us; speedup 1.0000x reference)
//
#include <hip/hip_runtime.h>
#include <stdint.h>

// RevGRU encoder, MI355X.
// R4: scan re-partitioned BY BATCH (4 WGs x 16 rows, 512 thr) -> zero cross-WG sync.
//   Recurrent weights pre-packed in MFMA B-frag order (split-bf16) by prep_rec and
//   streamed from L2 each step. h1/h2 + all staging in LDS; 4 __syncthreads per step.
//   Numerics identical to R3 (6-MFMA z, 3-MFMA g split schedules).
//   prep_x : transposed split-bf16 x-projection weights + bias; zero saved[0]
//   gemmx  : X[t*64+b][1536] = x @ [Wz1x|Wg1x|Wz2x|Wg2x] + bias  (unchanged)

typedef __attribute__((ext_vector_type(8))) short short8;
typedef __attribute__((ext_vector_type(4))) float floatx4;

#define MFMA16(a,b,c) __builtin_amdgcn_mfma_f32_16x16x32_bf16((a),(b),(c),0,0,0)

__device__ __forceinline__ short bf16_rne(float f) {
  uint32_t u = __float_as_uint(f);
  u += 0x7FFFu + ((u >> 16) & 1u);
  return (short)(u >> 16);
}
__device__ __forceinline__ float bf16f(short s) {
  return __uint_as_float(((uint32_t)(uint16_t)s) << 16);
}

#define SCALE_F 8388608.0f
#define INV_S   (1.0f/8388608.0f)

// ---- static device scratch (persist across calls; fully rewritten each call) ----
__device__ float g_X[50331648];      // 32768 x 1536  (201 MB)
__device__ float g_hs0f[16777216];   // 32768 x 512   (67 MB)
__device__ short g_WT_hi[786432];    // 1536 x 512 (x-proj, transposed)
__device__ short g_WT_lo[786432];
__device__ float g_bias[1536];
// recurrent weights packed in B-frag order: [nt][kf][term][lane][j]
__device__ __attribute__((aligned(16))) short g_wz1p[393216]; // 32nt x 8kf x 3t x 512
__device__ __attribute__((aligned(16))) short g_wz2p[393216];
__device__ __attribute__((aligned(16))) short g_wg1p[262144]; // 16nt x 8kf x 2t x 512
__device__ __attribute__((aligned(16))) short g_wg2p[262144];

// ------------------------------------------------------------------
__global__ void prep_x(const float* __restrict__ Wz1, const float* __restrict__ bz1,
                       const float* __restrict__ Wg1, const float* __restrict__ bg1,
                       const float* __restrict__ Wz2, const float* __restrict__ bz2,
                       const float* __restrict__ Wg2, const float* __restrict__ bg2,
                       int layer, int* __restrict__ d_out, int zero_extra) {
  int idx = blockIdx.x * 256 + threadIdx.x;   // grid covers 512*1536 exactly
  int k = idx / 1536;
  int c = idx - k * 1536;
  const float* W; const float* bb; int cc; int ncols;
  if (c < 512)       { W = Wz1; bb = bz1; cc = c;        ncols = 512; }
  else if (c < 768)  { W = Wg1; bb = bg1; cc = c - 512;  ncols = 256; }
  else if (c < 1280) { W = Wz2; bb = bz2; cc = c - 768;  ncols = 512; }
  else               { W = Wg2; bb = bg2; cc = c - 1280; ncols = 256; }
  float wv = W[(size_t)layer * 768 * ncols + (size_t)k * ncols + cc];
  short hi = bf16_rne(wv);
  short lo = bf16_rne(wv - bf16f(hi));
  g_WT_hi[(size_t)c * 512 + k] = hi;
  g_WT_lo[(size_t)c * 512 + k] = lo;
  if (k == 0) g_bias[c] = bb[layer * ncols + cc];
  if (zero_extra && idx < 6400) d_out[65536 + idx] = 0;   // saved[0] = h0 = zeros
}

// ------------------------------------------------------------------
// pack recurrent weights into MFMA B-frag order. 1536 blocks x 256 = 393216 threads.
__global__ void prep_rec(const float* __restrict__ Wz1, const float* __restrict__ Wg1,
                         const float* __restrict__ Wz2, const float* __restrict__ Wg2,
                         int layer) {
  int idx = blockIdx.x * 256 + threadIdx.x;
  if (idx < 262144) {                 // z1 / z2 (3-term)
    int which = idx >> 17;
    int e = idx & 131071;
    int nt = e >> 12; int rem = e & 4095;
    int kf = rem >> 9; int pos = rem & 511;
    int lane = pos >> 3; int j = pos & 7;
    int n = nt * 16 + (lane & 15);
    int k = kf * 32 + (lane >> 4) * 8 + j;
    const float* W = which ? Wz2 : Wz1;
    float v = W[(size_t)layer * 768 * 512 + (size_t)(512 + k) * 512 + n] * INV_S;
    short a0 = bf16_rne(v); float r1 = v - bf16f(a0);
    short a1 = bf16_rne(r1); float r2 = r1 - bf16f(a1);
    short a2 = bf16_rne(r2);
    short* dst = which ? g_wz2p : g_wz1p;
    int base = ((nt * 8 + kf) * 3) * 512 + pos;
    dst[base] = a0; dst[base + 512] = a1; dst[base + 1024] = a2;
  } else {                            // g1 / g2 (2-term)
    int e = idx - 262144;
    int which = e >> 16; e &= 65535;
    int nt = e >> 12; int rem = e & 4095;
    int kf = rem >> 9; int pos = rem & 511;
    int lane = pos >> 3; int j = pos & 7;
    int n = nt * 16 + (lane & 15);
    int k = kf * 32 + (lane >> 4) * 8 + j;
    const float* W = which ? Wg2 : Wg1;
    float v = W[(size_t)layer * 768 * 256 + (size_t)(512 + k) * 256 + n];
    short a0 = bf16_rne(v);
    short a1 = bf16_rne(v - bf16f(a0));
    short* dst = which ? g_wg2p : g_wg1p;
    int base = ((nt * 8 + kf) * 2) * 512 + pos;
    dst[base] = a0; dst[base + 512] = a1;
  }
}

// ------------------------------------------------------------------
__global__ __launch_bounds__(256)
void gemmx_kernel(const int* __restrict__ seq, const float* __restrict__ emb, int use_seq) {
  __shared__ float At[128][36];
  __shared__ short Bhi[128][40];
  __shared__ short Blo[128][40];
  __shared__ int toks[128];
  int tid = threadIdx.x;
  int r0 = blockIdx.x * 128;
  int c0 = blockIdx.y * 128;
  if (use_seq && tid < 128) toks[tid] = seq[r0 + tid];
  int lane = tid & 63;
  int wid = tid >> 6;
  int wm = wid & 1, wn = wid >> 1;
  int lm = lane & 15, lq = lane >> 4;
  floatx4 zero4 = {0.f, 0.f, 0.f, 0.f};
  floatx4 acc[4][4];
#pragma unroll
  for (int a = 0; a < 4; ++a)
#pragma unroll
    for (int b = 0; b < 4; ++b) acc[a][b] = zero4;
  __syncthreads();
  int am = tid >> 1;
  int ah = (tid & 1) * 16;
  const float* arow;
  if (use_seq) arow = emb + (size_t)toks[am] * 512;
  else         arow = g_hs0f + (size_t)(r0 + am) * 512;
  const short* bh_base = g_WT_hi + (size_t)(c0 + am) * 512;
  const short* bl_base = g_WT_lo + (size_t)(c0 + am) * 512;
  for (int kb = 0; kb < 16; ++kb) {
    int k0 = kb * 32 + ah;
    float4 a0 = *(const float4*)(arow + k0);
    float4 a1 = *(const float4*)(arow + k0 + 4);
    float4 a2 = *(const float4*)(arow + k0 + 8);
    float4 a3 = *(const float4*)(arow + k0 + 12);
    short4 b0 = *(const short4*)(bh_base + k0);
    short4 b1 = *(const short4*)(bh_base + k0 + 4);
    short4 b2 = *(const short4*)(bh_base + k0 + 8);
    short4 b3 = *(const short4*)(bh_base + k0 + 12);
    short4 l0 = *(const short4*)(bl_base + k0);
    short4 l1 = *(const short4*)(bl_base + k0 + 4);
    short4 l2 = *(const short4*)(bl_base + k0 + 8);
    short4 l3 = *(const short4*)(bl_base + k0 + 12);
    __syncthreads();
    *(float4*)&At[am][ah]      = a0;
    *(float4*)&At[am][ah + 4]  = a1;
    *(float4*)&At[am][ah + 8]  = a2;
    *(float4*)&At[am][ah + 12] = a3;
    *(short4*)&Bhi[am][ah]      = b0;
    *(short4*)&Bhi[am][ah + 4]  = b1;
    *(short4*)&Bhi[am][ah + 8]  = b2;
    *(short4*)&Bhi[am][ah + 12] = b3;
    *(short4*)&Blo[am][ah]      = l0;
    *(short4*)&Blo[am][ah + 4]  = l1;
    *(short4*)&Blo[am][ah + 8]  = l2;
    *(short4*)&Blo[am][ah + 12] = l3;
    __syncthreads();
    short8 afh[4], afl[4];
#pragma unroll
    for (int mt = 0; mt < 4; ++mt) {
      const float* ap = &At[wm*64 + mt*16 + lm][lq*8];
#pragma unroll
      for (int j = 0; j < 8; ++j) {
        float v = ap[j];
        short hi = bf16_rne(v);
        afh[mt][j] = hi;
        afl[mt][j] = bf16_rne(v - bf16f(hi));
      }
    }
#pragma unroll
    for (int nt = 0; nt < 4; ++nt) {
      short8 bfh = *(short8*)&Bhi[wn*64 + nt*16 + lm][lq*8];
      short8 bfl = *(short8*)&Blo[wn*64 + nt*16 + lm][lq*8];
#pragma unroll
      for (int mt = 0; mt < 4; ++mt) {
        acc[mt][nt] = MFMA16(afh[mt], bfh, acc[mt][nt]);
        acc[mt][nt] = MFMA16(afl[mt], bfh, acc[mt][nt]);
        acc[mt][nt] = MFMA16(afh[mt], bfl, acc[mt][nt]);
      }
    }
  }
#pragma unroll
  for (int nt = 0; nt < 4; ++nt) {
    int gc = c0 + wn*64 + nt*16 + lm;
    float bv = g_bias[gc];
#pragma unroll
    for (int mt = 0; mt < 4; ++mt) {
#pragma unroll
      for (int i = 0; i < 4; ++i) {
        int gr = r0 + wm*64 + mt*16 + lq*4 + i;
        g_X[(size_t)gr * 1536 + gc] = acc[mt][nt][i] + bv;
      }
    }
  }
}

// ------------------------------------------------------------------
// scan: one WG per 16 batch rows; all columns computed in-WG; no global sync.
__global__ __launch_bounds__(512, 2)
void scan_kernel(const int* __restrict__ lengths, int* __restrict__ d_out, int layer) {
  __shared__ int   h1i[16][260];
  __shared__ int   h2i[16][260];
  __shared__ int   zqs[16][260];
  __shared__ short za0[16][264], za1[16][264], za2[16][264]; // z A-split (h), ping-pong h2/h1
  __shared__ short ga0[16][264], ga1[16][264];               // g A-split (p)
  __shared__ int lens[16];

  int tid = threadIdx.x;
  int rb0 = blockIdx.x * 16;
  int lane = tid & 63, wv = tid >> 6;   // 8 waves
  int lm = lane & 15, lq = lane >> 4;

  if (tid < 16) lens[tid] = lengths[rb0 + tid];
  for (int i = tid; i < 16 * 260; i += 512) { ((int*)h1i)[i] = 0; ((int*)h2i)[i] = 0; }
  for (int i = tid; i < 16 * 264; i += 512) {
    ((short*)za0)[i] = 0; ((short*)za1)[i] = 0; ((short*)za2)[i] = 0;
  }
  __syncthreads();

  // X prefetch registers (current / next)
  float cxz1[4][4], cxg1[2][4], cxz2[4][4], cxg2[2][4];
  float nxz1[4][4], nxg1[2][4], nxz2[4][4], nxg2[2][4];

#define LDX(TT, XZ1, XG1, XZ2, XG2)                                              \
  {                                                                              \
    const float* base_ = g_X + ((size_t)((TT) * 64 + rb0) * 1536);               \
    _Pragma("unroll")                                                            \
    for (int a_ = 0; a_ < 4; ++a_) {                                             \
      int col_ = (wv + 8 * a_) * 16 + lm;                                        \
      _Pragma("unroll")                                                          \
      for (int i_ = 0; i_ < 4; ++i_) {                                           \
        XZ1[a_][i_] = base_[(size_t)(lq * 4 + i_) * 1536 + col_];                \
        XZ2[a_][i_] = base_[(size_t)(lq * 4 + i_) * 1536 + 768 + col_];          \
      }                                                                          \
    }                                                                            \
    _Pragma("unroll")                                                            \
    for (int a_ = 0; a_ < 2; ++a_) {                                             \
      int col_ = (wv + 8 * a_) * 16 + lm;                                        \
      _Pragma("unroll")                                                          \
      for (int i_ = 0; i_ < 4; ++i_) {                                           \
        XG1[a_][i_] = base_[(size_t)(lq * 4 + i_) * 1536 + 512 + col_];          \
        XG2[a_][i_] = base_[(size_t)(lq * 4 + i_) * 1536 + 1280 + col_];         \
      }                                                                          \
    }                                                                            \
  }

  LDX(0, cxz1, cxg1, cxz2, cxg2);

  for (int t = 0; t < 512; ++t) {
    int tn = (t + 1 < 512) ? t + 1 : t;
    LDX(tn, nxz1, nxg1, nxz2, nxg2);   // prefetch next step

    // ================= P1: z1 (A = h2 split in za*, p1 -> ga*, zq1 -> zqs) =====
    {
      floatx4 accz[4];
#pragma unroll
      for (int a = 0; a < 4; ++a) accz[a] = (floatx4){0.f, 0.f, 0.f, 0.f};
#pragma unroll
      for (int kf = 0; kf < 8; ++kf) {
        int ka = kf * 32 + lq * 8;
        short8 a0 = *(short8*)&za0[lm][ka];
        short8 a1 = *(short8*)&za1[lm][ka];
        short8 a2 = *(short8*)&za2[lm][ka];
#pragma unroll
        for (int a = 0; a < 4; ++a) {
          const short* bp = g_wz1p + ((size_t)(((wv + 8 * a) * 8 + kf) * 3)) * 512 + lane * 8;
          short8 b0 = *(const short8*)(bp);
          short8 b1 = *(const short8*)(bp + 512);
          short8 b2 = *(const short8*)(bp + 1024);
          accz[a] = MFMA16(a0, b0, accz[a]);
          accz[a] = MFMA16(a0, b1, accz[a]);
          accz[a] = MFMA16(a1, b0, accz[a]);
          accz[a] = MFMA16(a1, b1, accz[a]);
          accz[a] = MFMA16(a0, b2, accz[a]);
          accz[a] = MFMA16(a2, b0, accz[a]);
        }
      }
#pragma unroll
      for (int a = 0; a < 4; ++a) {
        int col = (wv + 8 * a) * 16 + lm;
#pragma unroll
        for (int i = 0; i < 4; ++i) {
          int r = lq * 4 + i;
          float pre = accz[a][i] + cxz1[a][i];
          float s = 1.0f / (1.0f + expf(-pre));
          if (a < 2) {
            float qf = floorf((0.875f * s + 0.125f) * 1024.0f);
            int qi = (int)qf; qi = qi < 1 ? 1 : (qi > 1024 ? 1024 : qi);
            zqs[r][col] = qi;
          } else {
            int c2 = col - 256;
            float p = s * ((float)h2i[r][c2] * INV_S);
            short p0 = bf16_rne(p);
            ga0[r][c2] = p0;
            ga1[r][c2] = bf16_rne(p - bf16f(p0));
          }
        }
      }
    }
    __syncthreads();

    // ================= P2: g1 + h1 update (writes h1 split -> za*) ============
    {
      floatx4 accg[2];
#pragma unroll
      for (int a = 0; a < 2; ++a) accg[a] = (floatx4){0.f, 0.f, 0.f, 0.f};
#pragma unroll
      for (int kf = 0; kf < 8; ++kf) {
        int ka = kf * 32 + lq * 8;
        short8 a0 = *(short8*)&ga0[lm][ka];
        short8 a1 = *(short8*)&ga1[lm][ka];
#pragma unroll
        for (int a = 0; a < 2; ++a) {
          const short* bp = g_wg1p + ((size_t)(((wv + 8 * a) * 8 + kf) * 2)) * 512 + lane * 8;
          short8 b0 = *(const short8*)(bp);
          short8 b1 = *(const short8*)(bp + 512);
          accg[a] = MFMA16(a0, b0, accg[a]);
          accg[a] = MFMA16(a1, b0, accg[a]);
          accg[a] = MFMA16(a0, b1, accg[a]);
        }
      }
#pragma unroll
      for (int a = 0; a < 2; ++a) {
        int col = (wv + 8 * a) * 16 + lm;
#pragma unroll
        for (int i = 0; i < 4; ++i) {
          int r = lq * 4 + i;
          float g = tanhf(accg[a][i] + cxg1[a][i]);
          int q = zqs[r][col];
          int hold = h1i[r][col];
          float zf = (float)q * (1.0f / 1024.0f);
          int ni = (int)rintf((1.0f - zf) * g * SCALE_F);
          int hnew = (hold >> 10) * q + (((hold & 1023) * q) >> 10) + ni;
          if (t >= lens[r]) hnew = hold;
          h1i[r][col] = hnew;
          float v = (float)hnew;
          short s0 = bf16_rne(v); float r1 = v - bf16f(s0);
          short s1 = bf16_rne(r1);
          za0[r][col] = s0; za1[r][col] = s1; za2[r][col] = bf16_rne(r1 - bf16f(s1));
          if (layer == 0) g_hs0f[(size_t)(t * 64 + rb0 + r) * 512 + col] = v * INV_S;
          else if (col < 100) d_out[65536 + (t + 1) * 6400 + (rb0 + r) * 100 + col] = hnew;
          if (t == 511) d_out[layer * 32768 + (rb0 + r) * 512 + col] = hnew;
        }
      }
    }
    __syncthreads();

    // ================= P3: z2 (A = h1 split in za*, p2 -> ga*, zq2 -> zqs) ====
    {
      floatx4 accz[4];
#pragma unroll
      for (int a = 0; a < 4; ++a) accz[a] = (floatx4){0.f, 0.f, 0.f, 0.f};
#pragma unroll
      for (int kf = 0; kf < 8; ++kf) {
        int ka = kf * 32 + lq * 8;
        short8 a0 = *(short8*)&za0[lm][ka];
        short8 a1 = *(short8*)&za1[lm][ka];
        short8 a2 = *(short8*)&za2[lm][ka];
#pragma unroll
        for (int a = 0; a < 4; ++a) {
          const short* bp = g_wz2p + ((size_t)(((wv + 8 * a) * 8 + kf) * 3)) * 512 + lane * 8;
          short8 b0 = *(const short8*)(bp);
          short8 b1 = *(const short8*)(bp + 512);
          short8 b2 = *(const short8*)(bp + 1024);
          accz[a] = MFMA16(a0, b0, accz[a]);
          accz[a] = MFMA16(a0, b1, accz[a]);
          accz[a] = MFMA16(a1, b0, accz[a]);
          accz[a] = MFMA16(a1, b1, accz[a]);
          accz[a] = MFMA16(a0, b2, accz[a]);
          accz[a] = MFMA16(a2, b0, accz[a]);
        }
      }
#pragma unroll
      for (int a = 0; a < 4; ++a) {
        int col = (wv + 8 * a) * 16 + lm;
#pragma unroll
        for (int i = 0; i < 4; ++i) {
          int r = lq * 4 + i;
          float pre = accz[a][i] + cxz2[a][i];
          float s = 1.0f / (1.0f + expf(-pre));
          if (a < 2) {
            float qf = floorf((0.875f * s + 0.125f) * 1024.0f);
            int qi = (int)qf; qi = qi < 1 ? 1 : (qi > 1024 ? 1024 : qi);
            zqs[r][col] = qi;
          } else {
            int c2 = col - 256;
            float p = s * ((float)h1i[r][c2] * INV_S);
            short p0 = bf16_rne(p);
            ga0[r][c2] = p0;
            ga1[r][c2] = bf16_rne(p - bf16f(p0));
          }
        }
      }
    }
    __syncthreads();

    // ================= P4: g2 + h2 update (writes h2 split -> za*) ============
    {
      floatx4 accg[2];
#pragma unroll
      for (int a = 0; a < 2; ++a) accg[a] = (floatx4){0.f, 0.f, 0.f, 0.f};
#pragma unroll
      for (int kf = 0; kf < 8; ++kf) {
        int ka = kf * 32 + lq * 8;
        short8 a0 = *(short8*)&ga0[lm][ka];
        short8 a1 = *(short8*)&ga1[lm][ka];
#pragma unroll
        for (int a = 0; a < 2; ++a) {
          const short* bp = g_wg2p + ((size_t)(((wv + 8 * a) * 8 + kf) * 2)) * 512 + lane * 8;
          short8 b0 = *(const short8*)(bp);
          short8 b1 = *(const short8*)(bp + 512);
          accg[a] = MFMA16(a0, b0, accg[a]);
          accg[a] = MFMA16(a1, b0, accg[a]);
          accg[a] = MFMA16(a0, b1, accg[a]);
        }
      }
#pragma unroll
      for (int a = 0; a < 2; ++a) {
        int col = (wv + 8 * a) * 16 + lm;
#pragma unroll
        for (int i = 0; i < 4; ++i) {
          int r = lq * 4 + i;
          float g = tanhf(accg[a][i] + cxg2[a][i]);
          int q = zqs[r][col];
          int hold = h2i[r][col];
          float zf = (float)q * (1.0f / 1024.0f);
          int ni = (int)rintf((1.0f - zf) * g * SCALE_F);
          int hnew = (hold >> 10) * q + (((hold & 1023) * q) >> 10) + ni;
          if (t >= lens[r]) hnew = hold;
          h2i[r][col] = hnew;
          float v = (float)hnew;
          short s0 = bf16_rne(v); float r1 = v - bf16f(s0);
          short s1 = bf16_rne(r1);
          za0[r][col] = s0; za1[r][col] = s1; za2[r][col] = bf16_rne(r1 - bf16f(s1));
          if (layer == 0) g_hs0f[(size_t)(t * 64 + rb0 + r) * 512 + 256 + col] = v * INV_S;
          if (t == 511) d_out[layer * 32768 + (rb0 + r) * 512 + 256 + col] = hnew;
        }
      }
    }
    __syncthreads();

    // rotate prefetch regs
#pragma unroll
    for (int a = 0; a < 4; ++a)
#pragma unroll
      for (int i = 0; i < 4; ++i) { cxz1[a][i] = nxz1[a][i]; cxz2[a][i] = nxz2[a][i]; }
#pragma unroll
    for (int a = 0; a < 2; ++a)
#pragma unroll
      for (int i = 0; i < 4; ++i) { cxg1[a][i] = nxg1[a][i]; cxg2[a][i] = nxg2[a][i]; }
  }
#undef LDX
}

// ------------------------------------------------------------------
extern "C" void kernel_launch(void* const* d_in, const int* in_sizes, int n_in,
                              void* d_out, int out_size, void* d_ws, size_t ws_size,
                              hipStream_t stream) {
  const int*   seq     = (const int*)d_in[0];
  const int*   lengths = (const int*)d_in[1];
  const float* emb     = (const float*)d_in[2];
  const float* Wz1     = (const float*)d_in[3];
  const float* bz1     = (const float*)d_in[4];
  const float* Wg1     = (const float*)d_in[5];
  const float* bg1     = (const float*)d_in[6];
  const float* Wz2     = (const float*)d_in[7];
  const float* bz2     = (const float*)d_in[8];
  const float* Wg2     = (const float*)d_in[9];
  const float* bg2     = (const float*)d_in[10];
  int* out = (int*)d_out;
  (void)in_sizes; (void)n_in; (void)out_size; (void)d_ws; (void)ws_size;

  for (int layer = 0; layer < 2; ++layer) {
    prep_x<<<3072, 256, 0, stream>>>(Wz1, bz1, Wg1, bg1, Wz2, bz2, Wg2, bg2,
                                     layer, out, layer == 0 ? 1 : 0);
    prep_rec<<<1536, 256, 0, stream>>>(Wz1, Wg1, Wz2, Wg2, layer);
    gemmx_kernel<<<dim3(256, 12), 256, 0, stream>>>(seq, emb, layer == 0 ? 1 : 0);
    scan_kernel<<<4, 512, 0, stream>>>(lengths, out, layer);
  }
}

// Round 5
// 19970.557 us; speedup vs baseline: 1.7546x; 1.7546x over previous
//
#include <hip/hip_runtime.h>
#include <stdint.h>

// RevGRU encoder, MI355X.
// R5: back to R3's column-partitioned scan (weights in registers), but cross-WG sync via
// SELF-VALIDATING TAGGED CHANNELS: every communicated word is 8B {tag,payload} stored with
// relaxed agent-scope atomics. No flags, no fences, no drain-before-flag. Readers poll the
// data itself (sentinel + bulk + straggler retry). 32 WGs = 4 domains x 8 col-groups x 512thr.
// R4 post-mortem: whole-domain-per-CU dies on weight BW (2.6MB/step through one CU).

typedef __attribute__((ext_vector_type(8))) short short8;
typedef __attribute__((ext_vector_type(4))) float floatx4;

#define MFMA16(a,b,c) __builtin_amdgcn_mfma_f32_16x16x32_bf16((a),(b),(c),0,0,0)

__device__ __forceinline__ short bf16_rne(float f) {
  uint32_t u = __float_as_uint(f);
  u += 0x7FFFu + ((u >> 16) & 1u);
  return (short)(u >> 16);
}
__device__ __forceinline__ float bf16f(short s) {
  return __uint_as_float(((uint32_t)(uint16_t)s) << 16);
}
__device__ __forceinline__ void st64(unsigned long long* p, unsigned long long v) {
  __hip_atomic_store(p, v, __ATOMIC_RELAXED, __HIP_MEMORY_SCOPE_AGENT);
}
__device__ __forceinline__ unsigned long long ld64(const unsigned long long* p) {
  return __hip_atomic_load(p, __ATOMIC_RELAXED, __HIP_MEMORY_SCOPE_AGENT);
}

#define SCALE_F 8388608.0f
#define INV_S   (1.0f/8388608.0f)

// ---- static device scratch (persist across calls; fully rewritten each call) ----
__device__ float g_X[50331648];      // 32768 x 1536  (201 MB)
__device__ float g_hs0f[16777216];   // 32768 x 512   (67 MB)
__device__ short g_WT_hi[786432];    // 1536 x 512 (x-proj, transposed)
__device__ short g_WT_lo[786432];
__device__ float g_bias[1536];
// tagged channels: [domain][6][16*256] : 0=Q1 1=P1 2=H1 3=Q2 4=P2 5=H2
__device__ unsigned long long g_ch[4][6][4096];

// ------------------------------------------------------------------
__global__ void prep_x(const float* __restrict__ Wz1, const float* __restrict__ bz1,
                       const float* __restrict__ Wg1, const float* __restrict__ bg1,
                       const float* __restrict__ Wz2, const float* __restrict__ bz2,
                       const float* __restrict__ Wg2, const float* __restrict__ bg2,
                       int layer, int* __restrict__ d_out, int zero_extra) {
  int idx = blockIdx.x * 256 + threadIdx.x;   // grid covers 512*1536 exactly
  int k = idx / 1536;
  int c = idx - k * 1536;
  const float* W; const float* bb; int cc; int ncols;
  if (c < 512)       { W = Wz1; bb = bz1; cc = c;        ncols = 512; }
  else if (c < 768)  { W = Wg1; bb = bg1; cc = c - 512;  ncols = 256; }
  else if (c < 1280) { W = Wz2; bb = bz2; cc = c - 768;  ncols = 512; }
  else               { W = Wg2; bb = bg2; cc = c - 1280; ncols = 256; }
  float wv = W[(size_t)layer * 768 * ncols + (size_t)k * ncols + cc];
  short hi = bf16_rne(wv);
  short lo = bf16_rne(wv - bf16f(hi));
  g_WT_hi[(size_t)c * 512 + k] = hi;
  g_WT_lo[(size_t)c * 512 + k] = lo;
  if (k == 0) g_bias[c] = bb[layer * ncols + cc];
  if (zero_extra && idx < 6400) d_out[65536 + idx] = 0;   // saved[0] = h0 = zeros
}

// ------------------------------------------------------------------
__global__ __launch_bounds__(256)
void gemmx_kernel(const int* __restrict__ seq, const float* __restrict__ emb, int use_seq) {
  __shared__ float At[128][36];
  __shared__ short Bhi[128][40];
  __shared__ short Blo[128][40];
  __shared__ int toks[128];
  int tid = threadIdx.x;
  int r0 = blockIdx.x * 128;
  int c0 = blockIdx.y * 128;
  if (use_seq && tid < 128) toks[tid] = seq[r0 + tid];
  int lane = tid & 63;
  int wid = tid >> 6;
  int wm = wid & 1, wn = wid >> 1;
  int lm = lane & 15, lq = lane >> 4;
  floatx4 zero4 = {0.f, 0.f, 0.f, 0.f};
  floatx4 acc[4][4];
#pragma unroll
  for (int a = 0; a < 4; ++a)
#pragma unroll
    for (int b = 0; b < 4; ++b) acc[a][b] = zero4;
  __syncthreads();
  int am = tid >> 1;
  int ah = (tid & 1) * 16;
  const float* arow;
  if (use_seq) arow = emb + (size_t)toks[am] * 512;
  else         arow = g_hs0f + (size_t)(r0 + am) * 512;
  const short* bh_base = g_WT_hi + (size_t)(c0 + am) * 512;
  const short* bl_base = g_WT_lo + (size_t)(c0 + am) * 512;
  for (int kb = 0; kb < 16; ++kb) {
    int k0 = kb * 32 + ah;
    float4 a0 = *(const float4*)(arow + k0);
    float4 a1 = *(const float4*)(arow + k0 + 4);
    float4 a2 = *(const float4*)(arow + k0 + 8);
    float4 a3 = *(const float4*)(arow + k0 + 12);
    short4 b0 = *(const short4*)(bh_base + k0);
    short4 b1 = *(const short4*)(bh_base + k0 + 4);
    short4 b2 = *(const short4*)(bh_base + k0 + 8);
    short4 b3 = *(const short4*)(bh_base + k0 + 12);
    short4 l0 = *(const short4*)(bl_base + k0);
    short4 l1 = *(const short4*)(bl_base + k0 + 4);
    short4 l2 = *(const short4*)(bl_base + k0 + 8);
    short4 l3 = *(const short4*)(bl_base + k0 + 12);
    __syncthreads();
    *(float4*)&At[am][ah]      = a0;
    *(float4*)&At[am][ah + 4]  = a1;
    *(float4*)&At[am][ah + 8]  = a2;
    *(float4*)&At[am][ah + 12] = a3;
    *(short4*)&Bhi[am][ah]      = b0;
    *(short4*)&Bhi[am][ah + 4]  = b1;
    *(short4*)&Bhi[am][ah + 8]  = b2;
    *(short4*)&Bhi[am][ah + 12] = b3;
    *(short4*)&Blo[am][ah]      = l0;
    *(short4*)&Blo[am][ah + 4]  = l1;
    *(short4*)&Blo[am][ah + 8]  = l2;
    *(short4*)&Blo[am][ah + 12] = l3;
    __syncthreads();
    short8 afh[4], afl[4];
#pragma unroll
    for (int mt = 0; mt < 4; ++mt) {
      const float* ap = &At[wm*64 + mt*16 + lm][lq*8];
#pragma unroll
      for (int j = 0; j < 8; ++j) {
        float v = ap[j];
        short hi = bf16_rne(v);
        afh[mt][j] = hi;
        afl[mt][j] = bf16_rne(v - bf16f(hi));
      }
    }
#pragma unroll
    for (int nt = 0; nt < 4; ++nt) {
      short8 bfh = *(short8*)&Bhi[wn*64 + nt*16 + lm][lq*8];
      short8 bfl = *(short8*)&Blo[wn*64 + nt*16 + lm][lq*8];
#pragma unroll
      for (int mt = 0; mt < 4; ++mt) {
        acc[mt][nt] = MFMA16(afh[mt], bfh, acc[mt][nt]);
        acc[mt][nt] = MFMA16(afl[mt], bfh, acc[mt][nt]);
        acc[mt][nt] = MFMA16(afh[mt], bfl, acc[mt][nt]);
      }
    }
  }
#pragma unroll
  for (int nt = 0; nt < 4; ++nt) {
    int gc = c0 + wn*64 + nt*16 + lm;
    float bv = g_bias[gc];
#pragma unroll
    for (int mt = 0; mt < 4; ++mt) {
#pragma unroll
      for (int i = 0; i < 4; ++i) {
        int gr = r0 + wm*64 + mt*16 + lq*4 + i;
        g_X[(size_t)gr * 1536 + gc] = acc[mt][nt][i] + bv;
      }
    }
  }
}

// ------------------------------------------------------------------
// scan: 32 WGs = 4 domains x 8 col-groups, 512 threads (8 waves).
// WG cg owns z-cols [cg*64, cg*64+64) and g/h-cols [cg*32, cg*32+32).
__global__ __launch_bounds__(512, 2)
void scan_kernel(const float* __restrict__ Wz1g, const float* __restrict__ Wg1g,
                 const float* __restrict__ Wz2g, const float* __restrict__ Wg2g,
                 const int* __restrict__ lengths, int* __restrict__ d_out, int layer) {
  __shared__ int   h1i[16][260];
  __shared__ int   h2i[16][260];
  __shared__ short phi[16][264];
  __shared__ short pmi[16][264];
  __shared__ short plo[16][264];
  __shared__ float redbuf[2304];
  __shared__ int lens[16];

  int tid = threadIdx.x;
  int wg = blockIdx.x;
  int dm = wg >> 3;       // batch domain 0..3
  int cg = wg & 7;        // column group 0..7
  int rb0 = dm * 16;
  int lane = tid & 63, wv = tid >> 6;   // 8 waves
  int lm = lane & 15, lq = lane >> 4;
  unsigned long long (*ch)[4096] = g_ch[dm];
  unsigned TB = (unsigned)(layer << 9);

  if (tid < 16) lens[tid] = lengths[rb0 + tid];
  for (int i = tid; i < 16 * 260; i += 512) { ((int*)h1i)[i] = 0; ((int*)h2i)[i] = 0; }

  // ---- preload recurrent-weight B-frags into registers (split-bf16) ----
  short8 wz1a[4], wz1b[4], wz1c[4], wz2a[4], wz2b[4], wz2c[4];
  short8 wg1a[2], wg1b[2], wg2a[2], wg2b[2];
  {
    int nt = wv & 3, kh = wv >> 2;
    int colz = cg * 64 + nt * 16 + lm;
    const float* W1 = Wz1g + (size_t)layer * 768 * 512 + (size_t)512 * 512 + colz;
    const float* W2 = Wz2g + (size_t)layer * 768 * 512 + (size_t)512 * 512 + colz;
#pragma unroll
    for (int ks = 0; ks < 4; ++ks) {
      int k0 = kh * 128 + ks * 32 + lq * 8;
      short8 t0, t1, t2, u0, u1, u2;
#pragma unroll
      for (int j = 0; j < 8; ++j) {
        float v = W1[(size_t)(k0 + j) * 512] * INV_S;   // pre-scale: A is raw int h
        short a0 = bf16_rne(v); float r1 = v - bf16f(a0);
        short a1 = bf16_rne(r1); float r2 = r1 - bf16f(a1);
        t0[j] = a0; t1[j] = a1; t2[j] = bf16_rne(r2);
        float v2 = W2[(size_t)(k0 + j) * 512] * INV_S;
        short d0 = bf16_rne(v2); float s1 = v2 - bf16f(d0);
        short d1 = bf16_rne(s1); float s2 = s1 - bf16f(d1);
        u0[j] = d0; u1[j] = d1; u2[j] = bf16_rne(s2);
      }
      wz1a[ks] = t0; wz1b[ks] = t1; wz1c[ks] = t2;
      wz2a[ks] = u0; wz2b[ks] = u1; wz2c[ks] = u2;
    }
    int ntg = wv & 1, kq = wv >> 1;
    int colg = cg * 32 + ntg * 16 + lm;
    const float* G1 = Wg1g + (size_t)layer * 768 * 256 + (size_t)512 * 256 + colg;
    const float* G2 = Wg2g + (size_t)layer * 768 * 256 + (size_t)512 * 256 + colg;
#pragma unroll
    for (int ks = 0; ks < 2; ++ks) {
      int k0 = kq * 64 + ks * 32 + lq * 8;
      short8 t0, t1, u0, u1;
#pragma unroll
      for (int j = 0; j < 8; ++j) {
        float v = G1[(size_t)(k0 + j) * 256];
        short a0 = bf16_rne(v);
        t0[j] = a0; t1[j] = bf16_rne(v - bf16f(a0));
        float v2 = G2[(size_t)(k0 + j) * 256];
        short d0 = bf16_rne(v2);
        u0[j] = d0; u1[j] = bf16_rne(v2 - bf16f(d0));
      }
      wg1a[ks] = t0; wg1b[ks] = t1; wg2a[ks] = u0; wg2b[ks] = u1;
    }
  }
  __syncthreads();

  int xr = tid & 15, xc = tid >> 4;   // xc 0..31
  int sr = tid >> 5, sc0 = (tid & 31) << 3;   // staging: 8 elems/thread

  auto ldx = [&](int tt, float& za, float& zb, float& g1x, float& ya, float& yb, float& g2x) {
    const float* base = g_X + (size_t)(tt * 64 + rb0 + xr) * 1536;
    float2 v1 = *(const float2*)(base + cg * 64 + 2 * xc);
    za = v1.x; zb = v1.y;
    g1x = base[512 + cg * 32 + xc];
    float2 v2 = *(const float2*)(base + 768 + cg * 64 + 2 * xc);
    ya = v2.x; yb = v2.y;
    g2x = base[1280 + cg * 32 + xc];
  };
  float cz1a, cz1b, cg1x, cz2a, cz2b, cg2x;
  ldx(0, cz1a, cz1b, cg1x, cz2a, cz2b, cg2x);

  // tagged bulk stage: 8 elems/thread, sentinel + bulk + straggler retry
#define STAGE8(CHIDX, EXP, DEPOSIT)                                            \
  {                                                                            \
    const unsigned long long* cp_ = &ch[CHIDX][sr * 256 + sc0];                \
    unsigned long long v_[8];                                                  \
    do { v_[0] = ld64(cp_); } while ((unsigned)(v_[0] >> 32) != (EXP));        \
    _Pragma("unroll")                                                          \
    for (int i_ = 1; i_ < 8; ++i_) v_[i_] = ld64(cp_ + i_);                    \
    unsigned pend_ = 0;                                                        \
    _Pragma("unroll")                                                          \
    for (int i_ = 1; i_ < 8; ++i_)                                             \
      if ((unsigned)(v_[i_] >> 32) != (EXP)) pend_ |= 1u << i_;                \
    while (pend_) {                                                            \
      __builtin_amdgcn_s_sleep(1);                                             \
      _Pragma("unroll")                                                        \
      for (int i_ = 1; i_ < 8; ++i_)                                           \
        if (pend_ & (1u << i_)) {                                              \
          v_[i_] = ld64(cp_ + i_);                                             \
          if ((unsigned)(v_[i_] >> 32) == (EXP)) pend_ &= ~(1u << i_);         \
        }                                                                      \
    }                                                                          \
    _Pragma("unroll")                                                          \
    for (int i_ = 0; i_ < 8; ++i_) { DEPOSIT; }                                \
  }

#define SPLIT3(SRC)                                                            \
  {                                                                            \
    _Pragma("unroll")                                                          \
    for (int i_ = 0; i_ < 8; ++i_) {                                           \
      float v = (float)SRC[sr][sc0 + i_];                                      \
      short a0 = bf16_rne(v); float r1 = v - bf16f(a0);                        \
      short a1 = bf16_rne(r1); float r2 = r1 - bf16f(a1);                      \
      phi[sr][sc0 + i_] = a0; pmi[sr][sc0 + i_] = a1;                          \
      plo[sr][sc0 + i_] = bf16_rne(r2);                                        \
    }                                                                          \
  }

  for (int t = 0; t < 512; ++t) {
    unsigned tagp = TB + (unsigned)t + 1u;
    float nz1a, nz1b, ng1x, nz2a, nz2b, ng2x;
    int tn = (t + 1 < 512) ? t + 1 : t;
    ldx(tn, nz1a, nz1b, ng1x, nz2a, nz2b, ng2x);   // prefetch next step's X

    // ================= P1: z1 =================
    if (t > 0) {
      STAGE8(5, TB + (unsigned)t, h2i[sr][sc0 + i_] = (int)(unsigned)v_[i_]);
    }
    SPLIT3(h2i);
    __syncthreads();
    {
      int nt = wv & 3, kh = wv >> 2;
      floatx4 acc = {0.f, 0.f, 0.f, 0.f};
#pragma unroll
      for (int ks = 0; ks < 4; ++ks) {
        int k0 = kh * 128 + ks * 32 + lq * 8;
        short8 a0 = *(short8*)&phi[lm][k0];
        short8 a1 = *(short8*)&pmi[lm][k0];
        short8 a2 = *(short8*)&plo[lm][k0];
        acc = MFMA16(a0, wz1a[ks], acc);
        acc = MFMA16(a0, wz1b[ks], acc);
        acc = MFMA16(a1, wz1a[ks], acc);
        acc = MFMA16(a1, wz1b[ks], acc);
        acc = MFMA16(a0, wz1c[ks], acc);
        acc = MFMA16(a2, wz1a[ks], acc);
      }
#pragma unroll
      for (int i = 0; i < 4; ++i) redbuf[kh * 1088 + (lq * 4 + i) * 68 + nt * 16 + lm] = acc[i];
    }
    __syncthreads();
    {
#pragma unroll
      for (int u = 0; u < 2; ++u) {
        int cc = 2 * xc + u;
        float pre = redbuf[xr * 68 + cc] + redbuf[1088 + xr * 68 + cc] + (u ? cz1b : cz1a);
        float s = 1.0f / (1.0f + expf(-pre));
        int gcol = cg * 64 + cc;
        if (gcol < 256) {
          float qf = floorf((0.875f * s + 0.125f) * 1024.0f);
          int qi = (int)qf; qi = qi < 1 ? 1 : (qi > 1024 ? 1024 : qi);
          st64(&ch[0][xr * 256 + gcol], ((unsigned long long)tagp << 32) | (unsigned)qi);
        } else {
          int rc = gcol - 256;
          float p = s * ((float)h2i[xr][rc] * INV_S);
          short p0 = bf16_rne(p);
          short p1s = bf16_rne(p - bf16f(p0));
          unsigned pay = ((unsigned)(unsigned short)p0 << 16) | (unsigned)(unsigned short)p1s;
          st64(&ch[1][xr * 256 + rc], ((unsigned long long)tagp << 32) | pay);
        }
      }
    }

    // ================= P2: g1 + h1 update =================
    int qv;
    STAGE8(1, tagp, { unsigned pl_ = (unsigned)v_[i_];
                      phi[sr][sc0 + i_] = (short)(pl_ >> 16);
                      plo[sr][sc0 + i_] = (short)(pl_ & 0xFFFFu); });
    {
      const unsigned long long* qp = &ch[0][xr * 256 + cg * 32 + xc];
      unsigned long long q64;
      do { q64 = ld64(qp); } while ((unsigned)(q64 >> 32) != tagp);
      qv = (int)(unsigned)q64;
    }
    __syncthreads();
    {
      int ntg = wv & 1, kq = wv >> 1;
      floatx4 acc = {0.f, 0.f, 0.f, 0.f};
#pragma unroll
      for (int ks = 0; ks < 2; ++ks) {
        int k0 = kq * 64 + ks * 32 + lq * 8;
        short8 a0 = *(short8*)&phi[lm][k0];
        short8 a1 = *(short8*)&plo[lm][k0];
        acc = MFMA16(a0, wg1a[ks], acc);
        acc = MFMA16(a1, wg1a[ks], acc);
        acc = MFMA16(a0, wg1b[ks], acc);
      }
#pragma unroll
      for (int i = 0; i < 4; ++i) redbuf[kq * 576 + (lq * 4 + i) * 36 + ntg * 16 + lm] = acc[i];
    }
    __syncthreads();
    {
      float pre = redbuf[xr * 36 + xc] + redbuf[576 + xr * 36 + xc]
                + redbuf[1152 + xr * 36 + xc] + redbuf[1728 + xr * 36 + xc] + cg1x;
      float g = tanhf(pre);
      int gc = cg * 32 + xc;
      int q = qv;
      int hold = h1i[xr][gc];
      float zf = (float)q * (1.0f / 1024.0f);
      int ni = (int)rintf((1.0f - zf) * g * SCALE_F);
      int hnew = (hold >> 10) * q + (((hold & 1023) * q) >> 10) + ni;
      if (t >= lens[xr]) hnew = hold;
      st64(&ch[2][xr * 256 + gc], ((unsigned long long)tagp << 32) | (unsigned)hnew);
      if (layer == 0) g_hs0f[(size_t)(t * 64 + rb0 + xr) * 512 + gc] = (float)hnew * INV_S;
      else if (gc < 100) d_out[65536 + (t + 1) * 6400 + (rb0 + xr) * 100 + gc] = hnew;
      if (t == 511) d_out[layer * 32768 + (rb0 + xr) * 512 + gc] = hnew;
    }
    __syncthreads();   // protect h1i old-value reads before P3 staging overwrites

    // ================= P3: z2 =================
    STAGE8(2, tagp, h1i[sr][sc0 + i_] = (int)(unsigned)v_[i_]);
    SPLIT3(h1i);
    __syncthreads();
    {
      int nt = wv & 3, kh = wv >> 2;
      floatx4 acc = {0.f, 0.f, 0.f, 0.f};
#pragma unroll
      for (int ks = 0; ks < 4; ++ks) {
        int k0 = kh * 128 + ks * 32 + lq * 8;
        short8 a0 = *(short8*)&phi[lm][k0];
        short8 a1 = *(short8*)&pmi[lm][k0];
        short8 a2 = *(short8*)&plo[lm][k0];
        acc = MFMA16(a0, wz2a[ks], acc);
        acc = MFMA16(a0, wz2b[ks], acc);
        acc = MFMA16(a1, wz2a[ks], acc);
        acc = MFMA16(a1, wz2b[ks], acc);
        acc = MFMA16(a0, wz2c[ks], acc);
        acc = MFMA16(a2, wz2a[ks], acc);
      }
#pragma unroll
      for (int i = 0; i < 4; ++i) redbuf[kh * 1088 + (lq * 4 + i) * 68 + nt * 16 + lm] = acc[i];
    }
    __syncthreads();
    {
#pragma unroll
      for (int u = 0; u < 2; ++u) {
        int cc = 2 * xc + u;
        float pre = redbuf[xr * 68 + cc] + redbuf[1088 + xr * 68 + cc] + (u ? cz2b : cz2a);
        float s = 1.0f / (1.0f + expf(-pre));
        int gcol = cg * 64 + cc;
        if (gcol < 256) {
          float qf = floorf((0.875f * s + 0.125f) * 1024.0f);
          int qi = (int)qf; qi = qi < 1 ? 1 : (qi > 1024 ? 1024 : qi);
          st64(&ch[3][xr * 256 + gcol], ((unsigned long long)tagp << 32) | (unsigned)qi);
        } else {
          int rc = gcol - 256;
          float p = s * ((float)h1i[xr][rc] * INV_S);
          short p0 = bf16_rne(p);
          short p1s = bf16_rne(p - bf16f(p0));
          unsigned pay = ((unsigned)(unsigned short)p0 << 16) | (unsigned)(unsigned short)p1s;
          st64(&ch[4][xr * 256 + rc], ((unsigned long long)tagp << 32) | pay);
        }
      }
    }

    // ================= P4: g2 + h2 update =================
    int qv2;
    STAGE8(4, tagp, { unsigned pl_ = (unsigned)v_[i_];
                      phi[sr][sc0 + i_] = (short)(pl_ >> 16);
                      plo[sr][sc0 + i_] = (short)(pl_ & 0xFFFFu); });
    {
      const unsigned long long* qp = &ch[3][xr * 256 + cg * 32 + xc];
      unsigned long long q64;
      do { q64 = ld64(qp); } while ((unsigned)(q64 >> 32) != tagp);
      qv2 = (int)(unsigned)q64;
    }
    __syncthreads();
    {
      int ntg = wv & 1, kq = wv >> 1;
      floatx4 acc = {0.f, 0.f, 0.f, 0.f};
#pragma unroll
      for (int ks = 0; ks < 2; ++ks) {
        int k0 = kq * 64 + ks * 32 + lq * 8;
        short8 a0 = *(short8*)&phi[lm][k0];
        short8 a1 = *(short8*)&plo[lm][k0];
        acc = MFMA16(a0, wg2a[ks], acc);
        acc = MFMA16(a1, wg2a[ks], acc);
        acc = MFMA16(a0, wg2b[ks], acc);
      }
#pragma unroll
      for (int i = 0; i < 4; ++i) redbuf[kq * 576 + (lq * 4 + i) * 36 + ntg * 16 + lm] = acc[i];
    }
    __syncthreads();
    {
      float pre = redbuf[xr * 36 + xc] + redbuf[576 + xr * 36 + xc]
                + redbuf[1152 + xr * 36 + xc] + redbuf[1728 + xr * 36 + xc] + cg2x;
      float g = tanhf(pre);
      int gc = cg * 32 + xc;
      int q = qv2;
      int hold = h2i[xr][gc];
      float zf = (float)q * (1.0f / 1024.0f);
      int ni = (int)rintf((1.0f - zf) * g * SCALE_F);
      int hnew = (hold >> 10) * q + (((hold & 1023) * q) >> 10) + ni;
      if (t >= lens[xr]) hnew = hold;
      st64(&ch[5][xr * 256 + gc], ((unsigned long long)tagp << 32) | (unsigned)hnew);
      if (layer == 0) g_hs0f[(size_t)(t * 64 + rb0 + xr) * 512 + 256 + gc] = (float)hnew * INV_S;
      if (t == 511) d_out[layer * 32768 + (rb0 + xr) * 512 + 256 + gc] = hnew;
    }
    __syncthreads();   // protect h2i old-value reads before next-step P1 staging

    cz1a = nz1a; cz1b = nz1b; cg1x = ng1x; cz2a = nz2a; cz2b = nz2b; cg2x = ng2x;
  }
#undef STAGE8
#undef SPLIT3
}

// ------------------------------------------------------------------
extern "C" void kernel_launch(void* const* d_in, const int* in_sizes, int n_in,
                              void* d_out, int out_size, void* d_ws, size_t ws_size,
                              hipStream_t stream) {
  const int*   seq     = (const int*)d_in[0];
  const int*   lengths = (const int*)d_in[1];
  const float* emb     = (const float*)d_in[2];
  const float* Wz1     = (const float*)d_in[3];
  const float* bz1     = (const float*)d_in[4];
  const float* Wg1     = (const float*)d_in[5];
  const float* bg1     = (const float*)d_in[6];
  const float* Wz2     = (const float*)d_in[7];
  const float* bz2     = (const float*)d_in[8];
  const float* Wg2     = (const float*)d_in[9];
  const float* bg2     = (const float*)d_in[10];
  int* out = (int*)d_out;
  (void)in_sizes; (void)n_in; (void)out_size; (void)d_ws; (void)ws_size;

  for (int layer = 0; layer < 2; ++layer) {
    prep_x<<<3072, 256, 0, stream>>>(Wz1, bz1, Wg1, bg1, Wz2, bz2, Wg2, bg2,
                                     layer, out, layer == 0 ? 1 : 0);
    gemmx_kernel<<<dim3(256, 12), 256, 0, stream>>>(seq, emb, layer == 0 ? 1 : 0);
    scan_kernel<<<32, 512, 0, stream>>>(Wz1, Wg1, Wz2, Wg2, lengths, out, layer);
  }
}

// Round 6
// 12355.553 us; speedup vs baseline: 2.8360x; 1.6163x over previous
//
#include <hip/hip_runtime.h>
#include <stdint.h>

// RevGRU encoder, MI355X.
// R6: LAYER-PIPELINED mega-kernel. R5 found a ~4.8us/hop cross-XCD rendezvous floor
// (invariant across flag- and tag-based protocols); 4 hops/step is inherent to the
// column-partitioned scan. So: run both layers CONCURRENTLY in one 112-WG kernel:
//   WG 0-31  : layer-0 scan (R5 structure, unchanged)       -> publishes tagged h0
//   WG 64-111: 48 X1-producers (per-step 16x128 GEMM slices, weights in regs)
//   WG 32-63 : layer-1 scan, consumes X1 from 32-deep tagged ring just-in-time
// Per-call epoch in every tag (replay-safe vs stale statics); producers throttle on
// L1 progress tags so the ring never clobbers unconsumed slots.

typedef __attribute__((ext_vector_type(8))) short short8;
typedef __attribute__((ext_vector_type(4))) float floatx4;

#define MFMA16(a,b,c) __builtin_amdgcn_mfma_f32_16x16x32_bf16((a),(b),(c),0,0,0)

__device__ __forceinline__ short bf16_rne(float f) {
  uint32_t u = __float_as_uint(f);
  u += 0x7FFFu + ((u >> 16) & 1u);
  return (short)(u >> 16);
}
__device__ __forceinline__ float bf16f(short s) {
  return __uint_as_float(((uint32_t)(uint16_t)s) << 16);
}
__device__ __forceinline__ void st64(unsigned long long* p, unsigned long long v) {
  __hip_atomic_store(p, v, __ATOMIC_RELAXED, __HIP_MEMORY_SCOPE_AGENT);
}
__device__ __forceinline__ unsigned long long ld64(const unsigned long long* p) {
  return __hip_atomic_load(p, __ATOMIC_RELAXED, __HIP_MEMORY_SCOPE_AGENT);
}

#define SCALE_F 8388608.0f
#define INV_S   (1.0f/8388608.0f)

// ---- static device scratch ----
__device__ float g_X[50331648];            // X0: 32768 x 1536 (layer-0 x-projections)
__device__ short g_WTh[2][786432];         // per-layer x-proj weights, transposed, split hi
__device__ short g_WTl[2][786432];         // split lo
__device__ float g_biasL[2][1536];
__device__ unsigned long long g_ch[2][4][6][4096];  // per-layer scan channels
__device__ unsigned long long g_h0s[16777216];      // [t][row][col] tagged {tag, f32 h0f}
__device__ unsigned long long g_x1r[3145728];       // ring [t&31][row][1536] tagged {tag, f32}
__device__ unsigned g_epoch;

__global__ void bump_epoch() { g_epoch = g_epoch + 1u; }

// ------------------------------------------------------------------
__global__ void prep_x(const float* __restrict__ Wz1, const float* __restrict__ bz1,
                       const float* __restrict__ Wg1, const float* __restrict__ bg1,
                       const float* __restrict__ Wz2, const float* __restrict__ bz2,
                       const float* __restrict__ Wg2, const float* __restrict__ bg2,
                       int layer, int* __restrict__ d_out, int zero_extra) {
  int idx = blockIdx.x * 256 + threadIdx.x;   // grid covers 512*1536 exactly
  int k = idx / 1536;
  int c = idx - k * 1536;
  const float* W; const float* bb; int cc; int ncols;
  if (c < 512)       { W = Wz1; bb = bz1; cc = c;        ncols = 512; }
  else if (c < 768)  { W = Wg1; bb = bg1; cc = c - 512;  ncols = 256; }
  else if (c < 1280) { W = Wz2; bb = bz2; cc = c - 768;  ncols = 512; }
  else               { W = Wg2; bb = bg2; cc = c - 1280; ncols = 256; }
  float wv = W[(size_t)layer * 768 * ncols + (size_t)k * ncols + cc];
  short hi = bf16_rne(wv);
  short lo = bf16_rne(wv - bf16f(hi));
  g_WTh[layer][(size_t)c * 512 + k] = hi;
  g_WTl[layer][(size_t)c * 512 + k] = lo;
  if (k == 0) g_biasL[layer][c] = bb[layer * ncols + cc];
  if (zero_extra && idx < 6400) d_out[65536 + idx] = 0;   // saved[0] = h0 = zeros
}

// ------------------------------------------------------------------
__global__ __launch_bounds__(256)
void gemmx_kernel(const int* __restrict__ seq, const float* __restrict__ emb) {
  __shared__ float At[128][36];
  __shared__ short Bhi[128][40];
  __shared__ short Blo[128][40];
  __shared__ int toks[128];
  int tid = threadIdx.x;
  int r0 = blockIdx.x * 128;
  int c0 = blockIdx.y * 128;
  if (tid < 128) toks[tid] = seq[r0 + tid];
  int lane = tid & 63;
  int wid = tid >> 6;
  int wm = wid & 1, wn = wid >> 1;
  int lm = lane & 15, lq = lane >> 4;
  floatx4 zero4 = {0.f, 0.f, 0.f, 0.f};
  floatx4 acc[4][4];
#pragma unroll
  for (int a = 0; a < 4; ++a)
#pragma unroll
    for (int b = 0; b < 4; ++b) acc[a][b] = zero4;
  __syncthreads();
  int am = tid >> 1;
  int ah = (tid & 1) * 16;
  const float* arow = emb + (size_t)toks[am] * 512;
  const short* bh_base = g_WTh[0] + (size_t)(c0 + am) * 512;
  const short* bl_base = g_WTl[0] + (size_t)(c0 + am) * 512;
  for (int kb = 0; kb < 16; ++kb) {
    int k0 = kb * 32 + ah;
    float4 a0 = *(const float4*)(arow + k0);
    float4 a1 = *(const float4*)(arow + k0 + 4);
    float4 a2 = *(const float4*)(arow + k0 + 8);
    float4 a3 = *(const float4*)(arow + k0 + 12);
    short4 b0 = *(const short4*)(bh_base + k0);
    short4 b1 = *(const short4*)(bh_base + k0 + 4);
    short4 b2 = *(const short4*)(bh_base + k0 + 8);
    short4 b3 = *(const short4*)(bh_base + k0 + 12);
    short4 l0 = *(const short4*)(bl_base + k0);
    short4 l1 = *(const short4*)(bl_base + k0 + 4);
    short4 l2 = *(const short4*)(bl_base + k0 + 8);
    short4 l3 = *(const short4*)(bl_base + k0 + 12);
    __syncthreads();
    *(float4*)&At[am][ah]      = a0;
    *(float4*)&At[am][ah + 4]  = a1;
    *(float4*)&At[am][ah + 8]  = a2;
    *(float4*)&At[am][ah + 12] = a3;
    *(short4*)&Bhi[am][ah]      = b0;
    *(short4*)&Bhi[am][ah + 4]  = b1;
    *(short4*)&Bhi[am][ah + 8]  = b2;
    *(short4*)&Bhi[am][ah + 12] = b3;
    *(short4*)&Blo[am][ah]      = l0;
    *(short4*)&Blo[am][ah + 4]  = l1;
    *(short4*)&Blo[am][ah + 8]  = l2;
    *(short4*)&Blo[am][ah + 12] = l3;
    __syncthreads();
    short8 afh[4], afl[4];
#pragma unroll
    for (int mt = 0; mt < 4; ++mt) {
      const float* ap = &At[wm*64 + mt*16 + lm][lq*8];
#pragma unroll
      for (int j = 0; j < 8; ++j) {
        float v = ap[j];
        short hi = bf16_rne(v);
        afh[mt][j] = hi;
        afl[mt][j] = bf16_rne(v - bf16f(hi));
      }
    }
#pragma unroll
    for (int nt = 0; nt < 4; ++nt) {
      short8 bfh = *(short8*)&Bhi[wn*64 + nt*16 + lm][lq*8];
      short8 bfl = *(short8*)&Blo[wn*64 + nt*16 + lm][lq*8];
#pragma unroll
      for (int mt = 0; mt < 4; ++mt) {
        acc[mt][nt] = MFMA16(afh[mt], bfh, acc[mt][nt]);
        acc[mt][nt] = MFMA16(afl[mt], bfh, acc[mt][nt]);
        acc[mt][nt] = MFMA16(afh[mt], bfl, acc[mt][nt]);
      }
    }
  }
#pragma unroll
  for (int nt = 0; nt < 4; ++nt) {
    int gc = c0 + wn*64 + nt*16 + lm;
    float bv = g_biasL[0][gc];
#pragma unroll
    for (int mt = 0; mt < 4; ++mt) {
#pragma unroll
      for (int i = 0; i < 4; ++i) {
        int gr = r0 + wm*64 + mt*16 + lq*4 + i;
        g_X[(size_t)gr * 1536 + gc] = acc[mt][nt][i] + bv;
      }
    }
  }
}

// ------------------------------------------------------------------
__global__ __launch_bounds__(512, 2)
void fused_kernel(const float* __restrict__ Wz1g, const float* __restrict__ Wg1g,
                  const float* __restrict__ Wz2g, const float* __restrict__ Wg2g,
                  const int* __restrict__ lengths, int* __restrict__ d_out) {
  __shared__ int   h1i[16][260];
  __shared__ int   h2i[16][260];
  __shared__ short phi[16][264];
  __shared__ short pmi[16][264];
  __shared__ short plo[16][264];
  __shared__ float redbuf[2304];
  __shared__ int lens[16];
  __shared__ short ahs[16][520];
  __shared__ short als[16][520];

  int tid = threadIdx.x;
  int bid = blockIdx.x;
  int lane = tid & 63, wv = tid >> 6;   // 8 waves
  int lm = lane & 15, lq = lane >> 4;
  unsigned ep = g_epoch;

  if (bid >= 64) {
    // ================== role: X1 producer (48 WGs) ==================
    int xw = bid - 64;
    int r4 = xw & 3;        // row tile (16 rows)
    int cs = xw >> 2;       // col slice (128 cols), 0..11
    int colx = cs * 128 + wv * 16 + lm;     // this lane's output column
    // preload B-frags (layer-1 x-proj weights), 16 kf x 2 terms
    short8 bh[16], bl[16];
#pragma unroll
    for (int kf = 0; kf < 16; ++kf) {
      bh[kf] = *(const short8*)&g_WTh[1][(size_t)colx * 512 + kf * 32 + lq * 8];
      bl[kf] = *(const short8*)&g_WTl[1][(size_t)colx * 512 + kf * 32 + lq * 8];
    }
    float bvx = g_biasL[1][colx];
    int sr2 = tid >> 5;             // row 0..15
    int cb  = (tid & 31) * 16;      // 16 cols each

    for (int t = 0; t < 512; ++t) {
      unsigned tagt = (ep << 10) | (unsigned)(t + 1);
      // stage A: poll h0s[t] rows r4*16..+16, split to LDS
      {
        const unsigned long long* hp = &g_h0s[((size_t)(t * 64) + r4 * 16 + sr2) * 512 + cb];
        unsigned long long v[16];
        do { v[0] = ld64(hp); } while ((unsigned)(v[0] >> 32) != tagt);
#pragma unroll
        for (int i = 1; i < 16; ++i) v[i] = ld64(hp + i);
        unsigned pend = 0;
#pragma unroll
        for (int i = 1; i < 16; ++i)
          if ((unsigned)(v[i] >> 32) != tagt) pend |= 1u << i;
        while (pend) {
          __builtin_amdgcn_s_sleep(1);
#pragma unroll
          for (int i = 1; i < 16; ++i)
            if (pend & (1u << i)) {
              v[i] = ld64(hp + i);
              if ((unsigned)(v[i] >> 32) == tagt) pend &= ~(1u << i);
            }
        }
#pragma unroll
        for (int i = 0; i < 16; ++i) {
          float f = __uint_as_float((unsigned)v[i]);
          short hi = bf16_rne(f);
          ahs[sr2][cb + i] = hi;
          als[sr2][cb + i] = bf16_rne(f - bf16f(hi));
        }
      }
      __syncthreads();
      floatx4 acc = {0.f, 0.f, 0.f, 0.f};
#pragma unroll
      for (int kf = 0; kf < 16; ++kf) {
        short8 a0 = *(short8*)&ahs[lm][kf * 32 + lq * 8];
        short8 a1 = *(short8*)&als[lm][kf * 32 + lq * 8];
        acc = MFMA16(a0, bh[kf], acc);
        acc = MFMA16(a1, bh[kf], acc);
        acc = MFMA16(a0, bl[kf], acc);
      }
      // throttle: don't clobber ring slots L1 hasn't consumed (window 24 of 32)
      if (t >= 25) {
        if (tid < 4) {
          unsigned need = (ep << 10) | (unsigned)(t - 24);
          while ((unsigned)(ld64(&g_ch[1][tid][5][0]) >> 32) < need) __builtin_amdgcn_s_sleep(2);
        }
      }
      __syncthreads();
#pragma unroll
      for (int i = 0; i < 4; ++i) {
        int row = r4 * 16 + lq * 4 + i;
        st64(&g_x1r[((size_t)(t & 31) * 64 + row) * 1536 + colx],
             ((unsigned long long)tagt << 32) | __float_as_uint(acc[i] + bvx));
      }
      __syncthreads();   // before next stage overwrites ahs/als
    }
    return;
  }

  // ================== role: scan (layer L), 32 WGs each ==================
  int L  = bid >> 5;
  int wg = bid & 31;
  int dm = wg >> 3;       // batch domain 0..3
  int cg = wg & 7;        // column group 0..7
  int rb0 = dm * 16;
  unsigned long long (*ch)[4096] = g_ch[L][dm];

  if (tid < 16) lens[tid] = lengths[rb0 + tid];
  for (int i = tid; i < 16 * 260; i += 512) { ((int*)h1i)[i] = 0; ((int*)h2i)[i] = 0; }

  // ---- preload recurrent-weight B-frags into registers (split-bf16) ----
  short8 wz1a[4], wz1b[4], wz1c[4], wz2a[4], wz2b[4], wz2c[4];
  short8 wg1a[2], wg1b[2], wg2a[2], wg2b[2];
  {
    int nt = wv & 3, kh = wv >> 2;
    int colz = cg * 64 + nt * 16 + lm;
    const float* W1 = Wz1g + (size_t)L * 768 * 512 + (size_t)512 * 512 + colz;
    const float* W2 = Wz2g + (size_t)L * 768 * 512 + (size_t)512 * 512 + colz;
#pragma unroll
    for (int ks = 0; ks < 4; ++ks) {
      int k0 = kh * 128 + ks * 32 + lq * 8;
      short8 t0, t1, t2, u0, u1, u2;
#pragma unroll
      for (int j = 0; j < 8; ++j) {
        float v = W1[(size_t)(k0 + j) * 512] * INV_S;   // pre-scale: A is raw int h
        short a0 = bf16_rne(v); float r1 = v - bf16f(a0);
        short a1 = bf16_rne(r1); float r2 = r1 - bf16f(a1);
        t0[j] = a0; t1[j] = a1; t2[j] = bf16_rne(r2);
        float v2 = W2[(size_t)(k0 + j) * 512] * INV_S;
        short d0 = bf16_rne(v2); float s1 = v2 - bf16f(d0);
        short d1 = bf16_rne(s1); float s2 = s1 - bf16f(d1);
        u0[j] = d0; u1[j] = d1; u2[j] = bf16_rne(s2);
      }
      wz1a[ks] = t0; wz1b[ks] = t1; wz1c[ks] = t2;
      wz2a[ks] = u0; wz2b[ks] = u1; wz2c[ks] = u2;
    }
    int ntg = wv & 1, kq = wv >> 1;
    int colg = cg * 32 + ntg * 16 + lm;
    const float* G1 = Wg1g + (size_t)L * 768 * 256 + (size_t)512 * 256 + colg;
    const float* G2 = Wg2g + (size_t)L * 768 * 256 + (size_t)512 * 256 + colg;
#pragma unroll
    for (int ks = 0; ks < 2; ++ks) {
      int k0 = kq * 64 + ks * 32 + lq * 8;
      short8 t0, t1, u0, u1;
#pragma unroll
      for (int j = 0; j < 8; ++j) {
        float v = G1[(size_t)(k0 + j) * 256];
        short a0 = bf16_rne(v);
        t0[j] = a0; t1[j] = bf16_rne(v - bf16f(a0));
        float v2 = G2[(size_t)(k0 + j) * 256];
        short d0 = bf16_rne(v2);
        u0[j] = d0; u1[j] = bf16_rne(v2 - bf16f(d0));
      }
      wg1a[ks] = t0; wg1b[ks] = t1; wg2a[ks] = u0; wg2b[ks] = u1;
    }
  }
  __syncthreads();

  int xr = tid & 15, xc = tid >> 4;   // xc 0..31
  int sr = tid >> 5, sc0 = (tid & 31) << 3;   // staging: 8 elems/thread

  auto ldx = [&](int tt, float& za, float& zb, float& g1x, float& ya, float& yb, float& g2x) {
    const float* base = g_X + (size_t)(tt * 64 + rb0 + xr) * 1536;
    float2 v1 = *(const float2*)(base + cg * 64 + 2 * xc);
    za = v1.x; zb = v1.y;
    g1x = base[512 + cg * 32 + xc];
    float2 v2 = *(const float2*)(base + 768 + cg * 64 + 2 * xc);
    ya = v2.x; yb = v2.y;
    g2x = base[1280 + cg * 32 + xc];
  };
  float cz1a = 0.f, cz1b = 0.f, cg1x = 0.f, cz2a = 0.f, cz2b = 0.f, cg2x = 0.f;
  if (L == 0) ldx(0, cz1a, cz1b, cg1x, cz2a, cz2b, cg2x);

#define STAGE8(CHIDX, EXP, DEPOSIT)                                            \
  {                                                                            \
    const unsigned long long* cp_ = &ch[CHIDX][sr * 256 + sc0];                \
    unsigned long long v_[8];                                                  \
    do { v_[0] = ld64(cp_); } while ((unsigned)(v_[0] >> 32) != (EXP));        \
    _Pragma("unroll")                                                          \
    for (int i_ = 1; i_ < 8; ++i_) v_[i_] = ld64(cp_ + i_);                    \
    unsigned pend_ = 0;                                                        \
    _Pragma("unroll")                                                          \
    for (int i_ = 1; i_ < 8; ++i_)                                             \
      if ((unsigned)(v_[i_] >> 32) != (EXP)) pend_ |= 1u << i_;                \
    while (pend_) {                                                            \
      __builtin_amdgcn_s_sleep(1);                                             \
      _Pragma("unroll")                                                        \
      for (int i_ = 1; i_ < 8; ++i_)                                           \
        if (pend_ & (1u << i_)) {                                              \
          v_[i_] = ld64(cp_ + i_);                                             \
          if ((unsigned)(v_[i_] >> 32) == (EXP)) pend_ &= ~(1u << i_);         \
        }                                                                      \
    }                                                                          \
    _Pragma("unroll")                                                          \
    for (int i_ = 0; i_ < 8; ++i_) { DEPOSIT; }                                \
  }

#define SPLIT3(SRC)                                                            \
  {                                                                            \
    _Pragma("unroll")                                                          \
    for (int i_ = 0; i_ < 8; ++i_) {                                           \
      float v = (float)SRC[sr][sc0 + i_];                                      \
      short a0 = bf16_rne(v); float r1 = v - bf16f(a0);                        \
      short a1 = bf16_rne(r1); float r2 = r1 - bf16f(a1);                      \
      phi[sr][sc0 + i_] = a0; pmi[sr][sc0 + i_] = a1;                          \
      plo[sr][sc0 + i_] = bf16_rne(r2);                                        \
    }                                                                          \
  }

  for (int t = 0; t < 512; ++t) {
    unsigned tagp = (ep << 10) | (unsigned)(t + 1);
    auto rdx = [&](int col) -> float {     // just-in-time tagged X1 read (layer 1)
      const unsigned long long* p = &g_x1r[((size_t)(t & 31) * 64 + rb0 + xr) * 1536 + col];
      unsigned long long v;
      do { v = ld64(p); } while ((unsigned)(v >> 32) != tagp);
      return __uint_as_float((unsigned)v);
    };
    float nz1a, nz1b, ng1x, nz2a, nz2b, ng2x;
    if (L == 0) {
      int tn = (t + 1 < 512) ? t + 1 : t;
      ldx(tn, nz1a, nz1b, ng1x, nz2a, nz2b, ng2x);   // prefetch next step's X0
    }

    // ================= P1: z1 =================
    if (t > 0) {
      STAGE8(5, (ep << 10) | (unsigned)t, h2i[sr][sc0 + i_] = (int)(unsigned)v_[i_]);
    }
    SPLIT3(h2i);
    __syncthreads();
    {
      int nt = wv & 3, kh = wv >> 2;
      floatx4 acc = {0.f, 0.f, 0.f, 0.f};
#pragma unroll
      for (int ks = 0; ks < 4; ++ks) {
        int k0 = kh * 128 + ks * 32 + lq * 8;
        short8 a0 = *(short8*)&phi[lm][k0];
        short8 a1 = *(short8*)&pmi[lm][k0];
        short8 a2 = *(short8*)&plo[lm][k0];
        acc = MFMA16(a0, wz1a[ks], acc);
        acc = MFMA16(a0, wz1b[ks], acc);
        acc = MFMA16(a1, wz1a[ks], acc);
        acc = MFMA16(a1, wz1b[ks], acc);
        acc = MFMA16(a0, wz1c[ks], acc);
        acc = MFMA16(a2, wz1a[ks], acc);
      }
#pragma unroll
      for (int i = 0; i < 4; ++i) redbuf[kh * 1088 + (lq * 4 + i) * 68 + nt * 16 + lm] = acc[i];
    }
    __syncthreads();
    {
      if (L == 1) { cz1a = rdx(cg * 64 + 2 * xc); cz1b = rdx(cg * 64 + 2 * xc + 1); }
#pragma unroll
      for (int u = 0; u < 2; ++u) {
        int cc = 2 * xc + u;
        float pre = redbuf[xr * 68 + cc] + redbuf[1088 + xr * 68 + cc] + (u ? cz1b : cz1a);
        float s = 1.0f / (1.0f + expf(-pre));
        int gcol = cg * 64 + cc;
        if (gcol < 256) {
          float qf = floorf((0.875f * s + 0.125f) * 1024.0f);
          int qi = (int)qf; qi = qi < 1 ? 1 : (qi > 1024 ? 1024 : qi);
          st64(&ch[0][xr * 256 + gcol], ((unsigned long long)tagp << 32) | (unsigned)qi);
        } else {
          int rc = gcol - 256;
          float p = s * ((float)h2i[xr][rc] * INV_S);
          short p0 = bf16_rne(p);
          short p1s = bf16_rne(p - bf16f(p0));
          unsigned pay = ((unsigned)(unsigned short)p0 << 16) | (unsigned)(unsigned short)p1s;
          st64(&ch[1][xr * 256 + rc], ((unsigned long long)tagp << 32) | pay);
        }
      }
    }

    // ================= P2: g1 + h1 update =================
    int qv;
    STAGE8(1, tagp, { unsigned pl_ = (unsigned)v_[i_];
                      phi[sr][sc0 + i_] = (short)(pl_ >> 16);
                      plo[sr][sc0 + i_] = (short)(pl_ & 0xFFFFu); });
    {
      const unsigned long long* qp = &ch[0][xr * 256 + cg * 32 + xc];
      unsigned long long q64;
      do { q64 = ld64(qp); } while ((unsigned)(q64 >> 32) != tagp);
      qv = (int)(unsigned)q64;
    }
    __syncthreads();
    {
      int ntg = wv & 1, kq = wv >> 1;
      floatx4 acc = {0.f, 0.f, 0.f, 0.f};
#pragma unroll
      for (int ks = 0; ks < 2; ++ks) {
        int k0 = kq * 64 + ks * 32 + lq * 8;
        short8 a0 = *(short8*)&phi[lm][k0];
        short8 a1 = *(short8*)&plo[lm][k0];
        acc = MFMA16(a0, wg1a[ks], acc);
        acc = MFMA16(a1, wg1a[ks], acc);
        acc = MFMA16(a0, wg1b[ks], acc);
      }
#pragma unroll
      for (int i = 0; i < 4; ++i) redbuf[kq * 576 + (lq * 4 + i) * 36 + ntg * 16 + lm] = acc[i];
    }
    __syncthreads();
    {
      if (L == 1) cg1x = rdx(512 + cg * 32 + xc);
      float pre = redbuf[xr * 36 + xc] + redbuf[576 + xr * 36 + xc]
                + redbuf[1152 + xr * 36 + xc] + redbuf[1728 + xr * 36 + xc] + cg1x;
      float g = tanhf(pre);
      int gc = cg * 32 + xc;
      int q = qv;
      int hold = h1i[xr][gc];
      float zf = (float)q * (1.0f / 1024.0f);
      int ni = (int)rintf((1.0f - zf) * g * SCALE_F);
      int hnew = (hold >> 10) * q + (((hold & 1023) * q) >> 10) + ni;
      if (t >= lens[xr]) hnew = hold;
      st64(&ch[2][xr * 256 + gc], ((unsigned long long)tagp << 32) | (unsigned)hnew);
      if (L == 0)
        st64(&g_h0s[((size_t)(t * 64) + rb0 + xr) * 512 + gc],
             ((unsigned long long)tagp << 32) | __float_as_uint((float)hnew * INV_S));
      else if (gc < 100) d_out[65536 + (t + 1) * 6400 + (rb0 + xr) * 100 + gc] = hnew;
      if (t == 511) d_out[L * 32768 + (rb0 + xr) * 512 + gc] = hnew;
    }
    __syncthreads();   // protect h1i old-value reads before P3 staging overwrites

    // ================= P3: z2 =================
    STAGE8(2, tagp, h1i[sr][sc0 + i_] = (int)(unsigned)v_[i_]);
    SPLIT3(h1i);
    __syncthreads();
    {
      int nt = wv & 3, kh = wv >> 2;
      floatx4 acc = {0.f, 0.f, 0.f, 0.f};
#pragma unroll
      for (int ks = 0; ks < 4; ++ks) {
        int k0 = kh * 128 + ks * 32 + lq * 8;
        short8 a0 = *(short8*)&phi[lm][k0];
        short8 a1 = *(short8*)&pmi[lm][k0];
        short8 a2 = *(short8*)&plo[lm][k0];
        acc = MFMA16(a0, wz2a[ks], acc);
        acc = MFMA16(a0, wz2b[ks], acc);
        acc = MFMA16(a1, wz2a[ks], acc);
        acc = MFMA16(a1, wz2b[ks], acc);
        acc = MFMA16(a0, wz2c[ks], acc);
        acc = MFMA16(a2, wz2a[ks], acc);
      }
#pragma unroll
      for (int i = 0; i < 4; ++i) redbuf[kh * 1088 + (lq * 4 + i) * 68 + nt * 16 + lm] = acc[i];
    }
    __syncthreads();
    {
      if (L == 1) { cz2a = rdx(768 + cg * 64 + 2 * xc); cz2b = rdx(768 + cg * 64 + 2 * xc + 1); }
#pragma unroll
      for (int u = 0; u < 2; ++u) {
        int cc = 2 * xc + u;
        float pre = redbuf[xr * 68 + cc] + redbuf[1088 + xr * 68 + cc] + (u ? cz2b : cz2a);
        float s = 1.0f / (1.0f + expf(-pre));
        int gcol = cg * 64 + cc;
        if (gcol < 256) {
          float qf = floorf((0.875f * s + 0.125f) * 1024.0f);
          int qi = (int)qf; qi = qi < 1 ? 1 : (qi > 1024 ? 1024 : qi);
          st64(&ch[3][xr * 256 + gcol], ((unsigned long long)tagp << 32) | (unsigned)qi);
        } else {
          int rc = gcol - 256;
          float p = s * ((float)h1i[xr][rc] * INV_S);
          short p0 = bf16_rne(p);
          short p1s = bf16_rne(p - bf16f(p0));
          unsigned pay = ((unsigned)(unsigned short)p0 << 16) | (unsigned)(unsigned short)p1s;
          st64(&ch[4][xr * 256 + rc], ((unsigned long long)tagp << 32) | pay);
        }
      }
    }

    // ================= P4: g2 + h2 update =================
    int qv2;
    STAGE8(4, tagp, { unsigned pl_ = (unsigned)v_[i_];
                      phi[sr][sc0 + i_] = (short)(pl_ >> 16);
                      plo[sr][sc0 + i_] = (short)(pl_ & 0xFFFFu); });
    {
      const unsigned long long* qp = &ch[3][xr * 256 + cg * 32 + xc];
      unsigned long long q64;
      do { q64 = ld64(qp); } while ((unsigned)(q64 >> 32) != tagp);
      qv2 = (int)(unsigned)q64;
    }
    __syncthreads();
    {
      int ntg = wv & 1, kq = wv >> 1;
      floatx4 acc = {0.f, 0.f, 0.f, 0.f};
#pragma unroll
      for (int ks = 0; ks < 2; ++ks) {
        int k0 = kq * 64 + ks * 32 + lq * 8;
        short8 a0 = *(short8*)&phi[lm][k0];
        short8 a1 = *(short8*)&plo[lm][k0];
        acc = MFMA16(a0, wg2a[ks], acc);
        acc = MFMA16(a1, wg2a[ks], acc);
        acc = MFMA16(a0, wg2b[ks], acc);
      }
#pragma unroll
      for (int i = 0; i < 4; ++i) redbuf[kq * 576 + (lq * 4 + i) * 36 + ntg * 16 + lm] = acc[i];
    }
    __syncthreads();
    {
      if (L == 1) cg2x = rdx(1280 + cg * 32 + xc);
      float pre = redbuf[xr * 36 + xc] + redbuf[576 + xr * 36 + xc]
                + redbuf[1152 + xr * 36 + xc] + redbuf[1728 + xr * 36 + xc] + cg2x;
      float g = tanhf(pre);
      int gc = cg * 32 + xc;
      int q = qv2;
      int hold = h2i[xr][gc];
      float zf = (float)q * (1.0f / 1024.0f);
      int ni = (int)rintf((1.0f - zf) * g * SCALE_F);
      int hnew = (hold >> 10) * q + (((hold & 1023) * q) >> 10) + ni;
      if (t >= lens[xr]) hnew = hold;
      st64(&ch[5][xr * 256 + gc], ((unsigned long long)tagp << 32) | (unsigned)hnew);
      if (L == 0)
        st64(&g_h0s[((size_t)(t * 64) + rb0 + xr) * 512 + 256 + gc],
             ((unsigned long long)tagp << 32) | __float_as_uint((float)hnew * INV_S));
      if (t == 511) d_out[L * 32768 + (rb0 + xr) * 512 + 256 + gc] = hnew;
    }
    __syncthreads();   // protect h2i old-value reads before next-step P1 staging

    if (L == 0) {
      cz1a = nz1a; cz1b = nz1b; cg1x = ng1x; cz2a = nz2a; cz2b = nz2b; cg2x = ng2x;
    }
  }
#undef STAGE8
#undef SPLIT3
}

// ------------------------------------------------------------------
extern "C" void kernel_launch(void* const* d_in, const int* in_sizes, int n_in,
                              void* d_out, int out_size, void* d_ws, size_t ws_size,
                              hipStream_t stream) {
  const int*   seq     = (const int*)d_in[0];
  const int*   lengths = (const int*)d_in[1];
  const float* emb     = (const float*)d_in[2];
  const float* Wz1     = (const float*)d_in[3];
  const float* bz1     = (const float*)d_in[4];
  const float* Wg1     = (const float*)d_in[5];
  const float* bg1     = (const float*)d_in[6];
  const float* Wz2     = (const float*)d_in[7];
  const float* bz2     = (const float*)d_in[8];
  const float* Wg2     = (const float*)d_in[9];
  const float* bg2     = (const float*)d_in[10];
  int* out = (int*)d_out;
  (void)in_sizes; (void)n_in; (void)out_size; (void)d_ws; (void)ws_size;

  bump_epoch<<<1, 1, 0, stream>>>();
  prep_x<<<3072, 256, 0, stream>>>(Wz1, bz1, Wg1, bg1, Wz2, bz2, Wg2, bg2, 0, out, 1);
  prep_x<<<3072, 256, 0, stream>>>(Wz1, bz1, Wg1, bg1, Wz2, bz2, Wg2, bg2, 1, out, 0);
  gemmx_kernel<<<dim3(256, 12), 256, 0, stream>>>(seq, emb);
  fused_kernel<<<112, 512, 0, stream>>>(Wz1, Wg1, Wz2, Wg2, lengths, out);
}